// Round 14
// baseline (8308.987 us; speedup 1.0000x reference)
//
#include <hip/hip_runtime.h>

typedef unsigned short u16;
typedef _Float16 f16x8 __attribute__((ext_vector_type(8)));
typedef float f32x4 __attribute__((ext_vector_type(4)));

#define T_LEN 512
#define BATCH 32
#define DIN 42
#define XPAD 64
#define HID 800
#define G4 3200
#define KCLS 20
#define NBLK 100
#define WSCAN 16
#define HSTR 1664        // padded h row stride (u16): fwd 0..799, bwd 832..1631
#define BOFF 832         // bwd column offset (128B-aligned)
#define KPAD 1632        // logical GEMM K: fwd 0..799, hole 800..831 (zeros), bwd 832..1631 -> B row k-32

__device__ __forceinline__ u16 f2h(float f){
    union { _Float16 h; u16 u; } v; v.h = (_Float16)f; return v.u;
}
__device__ __forceinline__ float sigm(float x){ return 1.f / (1.f + __expf(-x)); }
__device__ __forceinline__ float tanh_(float x){ return 2.f / (1.f + __expf(-2.f * x)) - 1.f; }

// ---------------- prep kernels ----------------
__global__ void k_cvt(const float* __restrict__ s, u16* __restrict__ d, int n){
    for (int i = blockIdx.x * blockDim.x + threadIdx.x; i < n; i += gridDim.x * blockDim.x)
        d[i] = f2h(s[i]);
}
__global__ void k_zero16(u16* __restrict__ d, int n){
    for (int i = blockIdx.x * blockDim.x + threadIdx.x; i < n; i += gridDim.x * blockDim.x)
        d[i] = 0;
}
// x (B,T,42) fp32 -> xT (T,B,64) f16, zero-padded
__global__ void k_xT(const float* __restrict__ x, u16* __restrict__ xT){
    const int n = T_LEN * BATCH * XPAD;
    for (int i = blockIdx.x * blockDim.x + threadIdx.x; i < n; i += gridDim.x * blockDim.x){
        int t = i / (BATCH * XPAD);
        int rem = i % (BATCH * XPAD);
        int b = rem / XPAD, k = rem % XPAD;
        xT[i] = (k < DIN) ? f2h(x[((size_t)b * T_LEN + t) * DIN + k]) : (u16)0;
    }
}
// pack whh (+optional wih appended as K-chunks 25..nkk-1) into fragment-ordered P2
__global__ void k_pack2(const float* __restrict__ whh, const float* __restrict__ wih,
                        int nkk, int kin, u16* __restrict__ P2){
    const int n_use = 50 * 2 * nkk * 2 * 64 * 8;
    for (int i = blockIdx.x * blockDim.x + threadIdx.x; i < n_use; i += gridDim.x * blockDim.x){
        int e = i & 7;
        int lane = (i >> 3) & 63;
        int which = (i >> 9) & 1;
        int r = i >> 10;
        int kk = r % nkk;
        int tn = r / nkk;
        int nh = tn & 1, tile = tn >> 1;
        int lr = lane & 15, kgrp = lane >> 4;
        int col = nh * 32 + which * 16 + lr;
        int gate = col >> 4, j = tile * 16 + (col & 15);
        float v;
        if (kk < 25){
            int k = kk * 32 + kgrp * 8 + e;
            v = whh[(size_t)(gate * 800 + j) * 800 + k];
        } else {
            int xk = (kk - 25) * 32 + kgrp * 8 + e;
            v = (xk < kin) ? wih[(size_t)(gate * 800 + j) * kin + xk] : 0.f;
        }
        P2[i] = f2h(v);
    }
}
// bias (3200) gate-major -> packed j*4+g fp32
__global__ void k_pack_bias(const float* __restrict__ b, float* __restrict__ bpk){
    for (int i = blockIdx.x * blockDim.x + threadIdx.x; i < G4; i += gridDim.x * blockDim.x){
        int g = i & 3, j = i >> 2;
        bpk[i] = b[g * 800 + j];
    }
}

// ---------------- device GEMM tile (128x128): C = A[M,K]*B[N,K]^T + bias ----------------
// At/Bt: LDS scratch (>= 128*40 u16 each). outmode: 0=f32, 2=f16 gate-packed cols.
__device__ void gemm_tile(
    u16* At, u16* Bt,
    const u16* __restrict__ Ag, int lda,
    const void* __restrict__ Bg_, int ldb,
    const float* __restrict__ bias,
    void* __restrict__ Cg, int ldc,
    int N, int K, int m0, int n0, int outmode, int b_is_f32, int khole)
{
    const u16*   Bu = (const u16*)Bg_;
    const float* Bf = (const float*)Bg_;
    const int tid = threadIdx.x;
    const int lane = tid & 63, w = tid >> 6;
    const int wr = w >> 1, wc = w & 1;
    const int lr = lane & 15, kb8 = (lane >> 4) * 8;
    const int sr = tid >> 1, skg = (tid & 1) << 4;
    f32x4 acc[4][4] = {};
    const int KT = (K + 31) >> 5;
    for (int kt = 0; kt < KT; ++kt){
        const int k0 = kt << 5;
        __syncthreads();
        { // stage A
            size_t base = (size_t)(m0 + sr) * lda + k0 + skg;
            const f16x8* p = (const f16x8*)(Ag + base);
            *(f16x8*)&At[sr * 40 + skg] = p[0];
            *(f16x8*)&At[sr * 40 + skg + 8] = p[1];
        }
        { // stage B
            int rn = n0 + sr;
            const int hole = khole && (k0 == 800);
            const int kb = (khole && k0 >= 832) ? (k0 - 32) : k0;
            if (rn < N && !hole && b_is_f32){
                size_t base = (size_t)rn * ldb + kb + skg;
                const float4* p = (const float4*)(Bf + base);
                float4 q0 = p[0], q1 = p[1], q2 = p[2], q3 = p[3];
                f16x8 v0, v1;
                v0[0] = (_Float16)q0.x; v0[1] = (_Float16)q0.y; v0[2] = (_Float16)q0.z; v0[3] = (_Float16)q0.w;
                v0[4] = (_Float16)q1.x; v0[5] = (_Float16)q1.y; v0[6] = (_Float16)q1.z; v0[7] = (_Float16)q1.w;
                v1[0] = (_Float16)q2.x; v1[1] = (_Float16)q2.y; v1[2] = (_Float16)q2.z; v1[3] = (_Float16)q2.w;
                v1[4] = (_Float16)q3.x; v1[5] = (_Float16)q3.y; v1[6] = (_Float16)q3.z; v1[7] = (_Float16)q3.w;
                *(f16x8*)&Bt[sr * 40 + skg] = v0;
                *(f16x8*)&Bt[sr * 40 + skg + 8] = v1;
            } else if (rn < N && !hole){
                size_t base = (size_t)rn * ldb + kb + skg;
                const f16x8* p = (const f16x8*)(Bu + base);
                *(f16x8*)&Bt[sr * 40 + skg] = p[0];
                *(f16x8*)&Bt[sr * 40 + skg + 8] = p[1];
            } else {
                f16x8 zv = {};
                *(f16x8*)&Bt[sr * 40 + skg] = zv;
                *(f16x8*)&Bt[sr * 40 + skg + 8] = zv;
            }
        }
        __syncthreads();
        f16x8 af[4], bfr[4];
        #pragma unroll
        for (int mi = 0; mi < 4; ++mi)
            af[mi] = *(const f16x8*)&At[(wr * 64 + mi * 16 + lr) * 40 + kb8];
        #pragma unroll
        for (int ni = 0; ni < 4; ++ni)
            bfr[ni] = *(const f16x8*)&Bt[(wc * 64 + ni * 16 + lr) * 40 + kb8];
        #pragma unroll
        for (int mi = 0; mi < 4; ++mi)
            #pragma unroll
            for (int ni = 0; ni < 4; ++ni)
                acc[mi][ni] = __builtin_amdgcn_mfma_f32_16x16x32_f16(af[mi], bfr[ni], acc[mi][ni], 0, 0, 0);
    }
    #pragma unroll
    for (int mi = 0; mi < 4; ++mi){
        #pragma unroll
        for (int ni = 0; ni < 4; ++ni){
            int col = n0 + wc * 64 + ni * 16 + lr;
            if (col >= N) continue;
            float bs = bias ? bias[col] : 0.f;
            int pc = (outmode == 2) ? ((col % 800) * 4 + col / 800) : col;
            #pragma unroll
            for (int r = 0; r < 4; ++r){
                int row = m0 + wr * 64 + mi * 16 + ((lane >> 4) * 4 + r);
                float v = acc[mi][ni][r] + bs;
                if (outmode) ((u16*)Cg)[(size_t)row * ldc + pc] = f2h(v);
                else         ((float*)Cg)[(size_t)row * ldc + pc] = v;
            }
        }
    }
}

// ---------------- standalone GEMM kernel (window-0 and logits) ----------------
__global__ __launch_bounds__(256) void mfma_gemm(
    const u16* __restrict__ A0, const u16* __restrict__ A1, int lda,
    const void* __restrict__ B0_, const void* __restrict__ B1_, int ldb,
    const float* __restrict__ bias0, const float* __restrict__ bias1,
    void* __restrict__ C0, void* __restrict__ C1, int ldc,
    int N, int K, int outmode, int b_is_f32, int khole)
{
    __shared__ u16 At[128 * 40];
    __shared__ u16 Bt[128 * 40];
    const int z = blockIdx.z;
    gemm_tile(At, Bt, z ? A1 : A0, lda, z ? B1_ : B0_, ldb, z ? bias1 : bias0,
              z ? C1 : C0, ldc, N, K, blockIdx.y * 128, blockIdx.x * 128,
              outmode, b_is_f32, khole);
}

// ---------------- scan step body (shared by layer-0 scan and fused kernel) ----------------
// (kept inline in each kernel to preserve the R11/R13-verified codegen)

// ---------------- layer-0 persistent scan (R13-proven form, nkk=27) ----------------
__global__ __launch_bounds__(256, 1) void scan_coop(
    const u16* __restrict__ xTp,
    const u16* __restrict__ P2f, const u16* __restrict__ P2b,
    const float* __restrict__ bpkF, const float* __restrict__ bpkB,
    const u16* __restrict__ hzero, u16* __restrict__ h,
    unsigned* __restrict__ arrive)
{
    const int nkk = 27;
    __shared__ u16 wlds[2 * 27 * 2 * 64 * 8];
    __shared__ float gLds[32][65];
    const int tid = threadIdx.x;
    const int dir = blockIdx.x & 1;
    const int tile = blockIdx.x >> 1;
    const u16* P2  = dir ? P2b : P2f;
    const float* bpk = dir ? bpkB : bpkF;

    const int wcnt = 2 * nkk * 2 * 64 * 8;
    {
        const u16* src = P2 + (size_t)tile * wcnt;
        for (int i = tid * 8; i < wcnt; i += 256 * 8)
            *(f16x8*)&wlds[i] = *(const f16x8*)&src[i];
    }
    __syncthreads();

    const int lane = tid & 63, w = tid >> 6;
    const int mi = w >> 1, nh = w & 1;
    const int lr = lane & 15, kb8 = (lane >> 4) * 8;
    const int arow = mi * 16 + lr;
    const int b_ep = tid >> 3;
    const int up   = (tid & 7) * 2;
    const int j    = tile * 16 + up;

    float c0 = 0.f, c1 = 0.f;
    f32x4 bb0 = *(const f32x4*)(bpk + j * 4);
    f32x4 bb1 = *(const f32x4*)(bpk + j * 4 + 4);
    const size_t hstep = (size_t)BATCH * HSTR;

    for (int s = 0; s < T_LEN; ++s){
        const int t = dir ? (T_LEN - 1 - s) : s;
        const u16* hprev = (s == 0) ? (hzero + dir * BOFF)
                           : (h + (size_t)(dir ? t + 1 : t - 1) * hstep + dir * BOFF);
        const u16* hp = hprev + (size_t)arow * HSTR + kb8;
        f16x8 areg[25];
        #pragma unroll
        for (int kk = 0; kk < 25; ++kk)
            areg[kk] = *(const f16x8*)(hp + kk * 32);
        f16x8 xa0, xa1;
        {
            const u16* xt = xTp + (size_t)t * (BATCH * XPAD) + arow * XPAD + kb8;
            xa0 = *(const f16x8*)(xt);
            xa1 = *(const f16x8*)(xt + 32);
        }
        f32x4 a0a = {}, a0b = {}, a1a = {}, a1b = {};
        #pragma unroll
        for (int kk = 0; kk < 24; kk += 2){
            f16x8 b0e = *(const f16x8*)&wlds[(size_t)((nh * nkk + kk) * 2 + 0) * 512 + lane * 8];
            f16x8 b1e = *(const f16x8*)&wlds[(size_t)((nh * nkk + kk) * 2 + 1) * 512 + lane * 8];
            f16x8 b0o = *(const f16x8*)&wlds[(size_t)((nh * nkk + kk + 1) * 2 + 0) * 512 + lane * 8];
            f16x8 b1o = *(const f16x8*)&wlds[(size_t)((nh * nkk + kk + 1) * 2 + 1) * 512 + lane * 8];
            a0a = __builtin_amdgcn_mfma_f32_16x16x32_f16(areg[kk],     b0e, a0a, 0, 0, 0);
            a1a = __builtin_amdgcn_mfma_f32_16x16x32_f16(areg[kk],     b1e, a1a, 0, 0, 0);
            a0b = __builtin_amdgcn_mfma_f32_16x16x32_f16(areg[kk + 1], b0o, a0b, 0, 0, 0);
            a1b = __builtin_amdgcn_mfma_f32_16x16x32_f16(areg[kk + 1], b1o, a1b, 0, 0, 0);
        }
        {
            f16x8 b0e = *(const f16x8*)&wlds[(size_t)((nh * nkk + 24) * 2 + 0) * 512 + lane * 8];
            f16x8 b1e = *(const f16x8*)&wlds[(size_t)((nh * nkk + 24) * 2 + 1) * 512 + lane * 8];
            a0a = __builtin_amdgcn_mfma_f32_16x16x32_f16(areg[24], b0e, a0a, 0, 0, 0);
            a1a = __builtin_amdgcn_mfma_f32_16x16x32_f16(areg[24], b1e, a1a, 0, 0, 0);
        }
        {
            f16x8 b0e = *(const f16x8*)&wlds[(size_t)((nh * nkk + 25) * 2 + 0) * 512 + lane * 8];
            f16x8 b1e = *(const f16x8*)&wlds[(size_t)((nh * nkk + 25) * 2 + 1) * 512 + lane * 8];
            a0b = __builtin_amdgcn_mfma_f32_16x16x32_f16(xa0, b0e, a0b, 0, 0, 0);
            a1b = __builtin_amdgcn_mfma_f32_16x16x32_f16(xa0, b1e, a1b, 0, 0, 0);
            f16x8 b0o = *(const f16x8*)&wlds[(size_t)((nh * nkk + 26) * 2 + 0) * 512 + lane * 8];
            f16x8 b1o = *(const f16x8*)&wlds[(size_t)((nh * nkk + 26) * 2 + 1) * 512 + lane * 8];
            a0a = __builtin_amdgcn_mfma_f32_16x16x32_f16(xa1, b0o, a0a, 0, 0, 0);
            a1a = __builtin_amdgcn_mfma_f32_16x16x32_f16(xa1, b1o, a1a, 0, 0, 0);
        }
        f32x4 acc0 = a0a + a0b;
        f32x4 acc1 = a1a + a1b;
        #pragma unroll
        for (int r = 0; r < 4; ++r){
            int b = mi * 16 + (lane >> 4) * 4 + r;
            gLds[b][nh * 32 + lr]      = acc0[r];
            gLds[b][nh * 32 + 16 + lr] = acc1[r];
        }
        __syncthreads();
        {
            float gi0 = gLds[b_ep][up]          + bb0[0];
            float gf0 = gLds[b_ep][16 + up]     + bb0[1];
            float gg0 = gLds[b_ep][32 + up]     + bb0[2];
            float go0 = gLds[b_ep][48 + up]     + bb0[3];
            float gi1 = gLds[b_ep][up + 1]      + bb1[0];
            float gf1 = gLds[b_ep][16 + up + 1] + bb1[1];
            float gg1 = gLds[b_ep][32 + up + 1] + bb1[2];
            float go1 = gLds[b_ep][48 + up + 1] + bb1[3];
            float cn0 = sigm(gf0) * c0 + sigm(gi0) * tanh_(gg0);
            float cn1 = sigm(gf1) * c1 + sigm(gi1) * tanh_(gg1);
            c0 = cn0; c1 = cn1;
            union { unsigned u; _Float16 hh[2]; } pk;
            pk.hh[0] = (_Float16)(sigm(go0) * tanh_(cn0));
            pk.hh[1] = (_Float16)(sigm(go1) * tanh_(cn1));
            unsigned* dst = (unsigned*)(h + (size_t)t * hstep + dir * BOFF + (size_t)b_ep * HSTR + j);
            __hip_atomic_store(dst, pk.u, __ATOMIC_RELAXED, __HIP_MEMORY_SCOPE_AGENT);
        }
        if (s != T_LEN - 1){
            const unsigned tgt = (unsigned)(s + 1);
            __syncthreads();
            if (tid == 0)
                __hip_atomic_store(arrive + (size_t)blockIdx.x * 32, tgt,
                                   __ATOMIC_RELAXED, __HIP_MEMORY_SCOPE_AGENT);
            if (tid < 64){
                const unsigned* slot = arrive + (size_t)(((tid < 50) ? tid : 0) * 2 + dir) * 32;
                while (true){
                    unsigned v = __hip_atomic_load(slot, __ATOMIC_RELAXED, __HIP_MEMORY_SCOPE_AGENT);
                    if (__all((int)(v >= tgt))) break;
                    __builtin_amdgcn_s_sleep(1);
                }
            }
            __syncthreads();
        }
    }
}

// ---------------- fused: layer-1 scan (blocks 0..99) + next-window dual GEMM (blocks 100..199) --
__global__ __launch_bounds__(256, 1) void scan_fused(
    int s0,
    const u16* __restrict__ xgF, const u16* __restrict__ xgB,
    const u16* __restrict__ P2f, const u16* __restrict__ P2b,
    const u16* __restrict__ hzero, u16* __restrict__ h,
    float* __restrict__ cF, float* __restrict__ cB,
    int cload, unsigned* __restrict__ arrive,
    // gemm part (next window)
    int have_next,
    const u16* __restrict__ A0n, const u16* __restrict__ A1n,
    const float* __restrict__ wih1f, const float* __restrict__ wih1b,
    const float* __restrict__ b1f, const float* __restrict__ b1b,
    u16* __restrict__ xgFn, u16* __restrict__ xgBn)
{
    const int nkk = 25;
    __shared__ u16 wlds[2 * 27 * 2 * 64 * 8];   // scan weights / gemm At+Bt union
    __shared__ float gLds[32][65];
    const int tid = threadIdx.x;

    if (blockIdx.x >= NBLK){
        // ---------- GEMM path ----------
        if (!have_next) return;
        u16* At = wlds;
        u16* Bt = wlds + 128 * 40;
        const int gid = blockIdx.x - NBLK;   // 0..99
        const int z   = gid & 1;
        const int grp = gid >> 1;            // 0..49
        const int cb  = grp % 25;
        const int mh  = grp / 25;            // 0..1
        const u16* Ag = z ? A1n : A0n;
        const float* Bw = z ? wih1b : wih1f;
        const float* bs = z ? b1b : b1f;
        u16* Cg = z ? xgBn : xgFn;
        #pragma unroll
        for (int mt = 0; mt < 2; ++mt){
            int m0 = (mh * 2 + mt) * 128;
            gemm_tile(At, Bt, Ag, HSTR, Bw, 1600, bs, Cg, G4,
                      G4, KPAD, m0, cb * 128, 2, 1, 1);
        }
        return;
    }

    // ---------- scan path (identical to R13 layer-1 scan) ----------
    const int dir = blockIdx.x & 1;
    const int tile = blockIdx.x >> 1;
    const u16* P2  = dir ? P2b : P2f;
    const u16* xg  = dir ? xgB : xgF;
    float* cst = dir ? cB : cF;

    const int wcnt = 2 * nkk * 2 * 64 * 8;
    {
        const u16* src = P2 + (size_t)tile * wcnt;
        for (int i = tid * 8; i < wcnt; i += 256 * 8)
            *(f16x8*)&wlds[i] = *(const f16x8*)&src[i];
    }
    __syncthreads();

    const int lane = tid & 63, w = tid >> 6;
    const int mi = w >> 1, nh = w & 1;
    const int lr = lane & 15, kb8 = (lane >> 4) * 8;
    const int arow = mi * 16 + lr;
    const int b_ep = tid >> 3;
    const int up   = (tid & 7) * 2;
    const int j    = tile * 16 + up;

    float c0 = 0.f, c1 = 0.f;
    if (cload){
        c0 = cst[tile * 512 + tid * 2];
        c1 = cst[tile * 512 + tid * 2 + 1];
    }
    const size_t hstep = (size_t)BATCH * HSTR;

    for (int q = 0; q < WSCAN; ++q){
        const int s = s0 + q;
        const int t = dir ? (T_LEN - 1 - s) : s;
        const u16* hprev = (s == 0) ? (hzero + dir * BOFF)
                           : (h + (size_t)(dir ? t + 1 : t - 1) * hstep + dir * BOFF);
        const u16* hp = hprev + (size_t)arow * HSTR + kb8;
        f16x8 areg[25];
        #pragma unroll
        for (int kk = 0; kk < 25; ++kk)
            areg[kk] = *(const f16x8*)(hp + kk * 32);
        const int qq = dir ? (WSCAN - 1 - q) : q;
        f16x8 xv = *(const f16x8*)(xg + ((size_t)qq * BATCH + b_ep) * G4 + j * 4);

        f32x4 a0a = {}, a0b = {}, a1a = {}, a1b = {};
        #pragma unroll
        for (int kk = 0; kk < 24; kk += 2){
            f16x8 b0e = *(const f16x8*)&wlds[(size_t)((nh * nkk + kk) * 2 + 0) * 512 + lane * 8];
            f16x8 b1e = *(const f16x8*)&wlds[(size_t)((nh * nkk + kk) * 2 + 1) * 512 + lane * 8];
            f16x8 b0o = *(const f16x8*)&wlds[(size_t)((nh * nkk + kk + 1) * 2 + 0) * 512 + lane * 8];
            f16x8 b1o = *(const f16x8*)&wlds[(size_t)((nh * nkk + kk + 1) * 2 + 1) * 512 + lane * 8];
            a0a = __builtin_amdgcn_mfma_f32_16x16x32_f16(areg[kk],     b0e, a0a, 0, 0, 0);
            a1a = __builtin_amdgcn_mfma_f32_16x16x32_f16(areg[kk],     b1e, a1a, 0, 0, 0);
            a0b = __builtin_amdgcn_mfma_f32_16x16x32_f16(areg[kk + 1], b0o, a0b, 0, 0, 0);
            a1b = __builtin_amdgcn_mfma_f32_16x16x32_f16(areg[kk + 1], b1o, a1b, 0, 0, 0);
        }
        {
            f16x8 b0e = *(const f16x8*)&wlds[(size_t)((nh * nkk + 24) * 2 + 0) * 512 + lane * 8];
            f16x8 b1e = *(const f16x8*)&wlds[(size_t)((nh * nkk + 24) * 2 + 1) * 512 + lane * 8];
            a0a = __builtin_amdgcn_mfma_f32_16x16x32_f16(areg[24], b0e, a0a, 0, 0, 0);
            a1a = __builtin_amdgcn_mfma_f32_16x16x32_f16(areg[24], b1e, a1a, 0, 0, 0);
        }
        f32x4 acc0 = a0a + a0b;
        f32x4 acc1 = a1a + a1b;
        #pragma unroll
        for (int r = 0; r < 4; ++r){
            int b = mi * 16 + (lane >> 4) * 4 + r;
            gLds[b][nh * 32 + lr]      = acc0[r];
            gLds[b][nh * 32 + 16 + lr] = acc1[r];
        }
        __syncthreads();
        {
            float gi0 = gLds[b_ep][up]          + (float)xv[0];
            float gf0 = gLds[b_ep][16 + up]     + (float)xv[1];
            float gg0 = gLds[b_ep][32 + up]     + (float)xv[2];
            float go0 = gLds[b_ep][48 + up]     + (float)xv[3];
            float gi1 = gLds[b_ep][up + 1]      + (float)xv[4];
            float gf1 = gLds[b_ep][16 + up + 1] + (float)xv[5];
            float gg1 = gLds[b_ep][32 + up + 1] + (float)xv[6];
            float go1 = gLds[b_ep][48 + up + 1] + (float)xv[7];
            float cn0 = sigm(gf0) * c0 + sigm(gi0) * tanh_(gg0);
            float cn1 = sigm(gf1) * c1 + sigm(gi1) * tanh_(gg1);
            c0 = cn0; c1 = cn1;
            union { unsigned u; _Float16 hh[2]; } pk;
            pk.hh[0] = (_Float16)(sigm(go0) * tanh_(cn0));
            pk.hh[1] = (_Float16)(sigm(go1) * tanh_(cn1));
            unsigned* dst = (unsigned*)(h + (size_t)t * hstep + dir * BOFF + (size_t)b_ep * HSTR + j);
            __hip_atomic_store(dst, pk.u, __ATOMIC_RELAXED, __HIP_MEMORY_SCOPE_AGENT);
        }
        if (q != WSCAN - 1){
            const unsigned tgt = (unsigned)(s + 1);
            __syncthreads();
            if (tid == 0)
                __hip_atomic_store(arrive + (size_t)blockIdx.x * 32, tgt,
                                   __ATOMIC_RELAXED, __HIP_MEMORY_SCOPE_AGENT);
            if (tid < 64){
                const unsigned* slot = arrive + (size_t)(((tid < 50) ? tid : 0) * 2 + dir) * 32;
                while (true){
                    unsigned v = __hip_atomic_load(slot, __ATOMIC_RELAXED, __HIP_MEMORY_SCOPE_AGENT);
                    if (__all((int)(v >= tgt))) break;
                    __builtin_amdgcn_s_sleep(1);
                }
            }
            __syncthreads();
        }
    }
    cst[tile * 512 + tid * 2]     = c0;
    cst[tile * 512 + tid * 2 + 1] = c1;
}

// ---------------- softmax over batch + angles ----------------
__global__ __launch_bounds__(64) void k_smax_ang(
    const float* __restrict__ logits, const float* __restrict__ alphabet,
    float* __restrict__ ang)
{
    int t = blockIdx.x;
    __shared__ float P[32][20];
    __shared__ float sA[20][3], cA[20][3];
    int tid = threadIdx.x;
    for (int idx = tid; idx < 32 * 20; idx += 64){
        int b = idx / 20, k = idx % 20;
        P[b][k] = logits[((size_t)t * 32 + b) * 20 + k];
    }
    for (int idx = tid; idx < 60; idx += 64){
        float al = alphabet[idx];
        sA[idx / 3][idx % 3] = sinf(al);
        cA[idx / 3][idx % 3] = cosf(al);
    }
    __syncthreads();
    if (tid < 20){
        float mx = -1e30f;
        for (int b = 0; b < 32; ++b) mx = fmaxf(mx, P[b][tid]);
        float s = 0.f;
        for (int b = 0; b < 32; ++b){ float e = __expf(P[b][tid] - mx); P[b][tid] = e; s += e; }
        float inv = 1.f / s;
        for (int b = 0; b < 32; ++b) P[b][tid] *= inv;
    }
    __syncthreads();
    if (tid < 32){
        float sx = 0, sy = 0, sz = 0, cx = 0, cy = 0, cz = 0;
        for (int k = 0; k < 20; ++k){
            float p = P[tid][k];
            sx += p * sA[k][0]; sy += p * sA[k][1]; sz += p * sA[k][2];
            cx += p * cA[k][0]; cy += p * cA[k][1]; cz += p * cA[k][2];
        }
        size_t base = ((size_t)t * 32 + tid) * 3;
        ang[base + 0] = atan2f(sx, cx);
        ang[base + 1] = atan2f(sy, cy);
        ang[base + 2] = atan2f(sz, cz);
    }
}

// ---------------- sequential coordinate chain ----------------
__global__ __launch_bounds__(64) void k_coords(const float* __restrict__ ang, float* __restrict__ out){
    int b = threadIdx.x;
    if (b >= 32) return;
    float ax = 0.f, ay = 0.f, az = 1.f;
    float bx = 0.f, by = 1.f, bz = 1.f;
    float cx = 1.f, cy = 1.f, cz = 1.f;
    out[(0 * 32 + b) * 3 + 0] = ax; out[(0 * 32 + b) * 3 + 1] = ay; out[(0 * 32 + b) * 3 + 2] = az;
    out[(1 * 32 + b) * 3 + 0] = bx; out[(1 * 32 + b) * 3 + 1] = by; out[(1 * 32 + b) * 3 + 2] = bz;
    out[(2 * 32 + b) * 3 + 0] = cx; out[(2 * 32 + b) * 3 + 1] = cy; out[(2 * 32 + b) * 3 + 2] = cz;
    const float rr[3] = {145.801f, 152.326f, 132.868f};
    const float ba[3] = {2.124f, 1.941f, 2.028f};
    float ct[3], st[3];
    #pragma unroll
    for (int i = 0; i < 3; ++i){ ct[i] = cosf(ba[i]); st[i] = sinf(ba[i]); }
    for (int t = 0; t < T_LEN; ++t){
        #pragma unroll
        for (int i = 0; i < 3; ++i){
            float p = ang[((size_t)t * 32 + b) * 3 + i];
            float d2x = -rr[i] * ct[i];
            float d2y = rr[i] * cosf(p) * st[i];
            float d2z = rr[i] * sinf(p) * st[i];
            float bcx = cx - bx, bcy = cy - by, bcz = cz - bz;
            float inb = 1.f / sqrtf(bcx * bcx + bcy * bcy + bcz * bcz);
            bcx *= inb; bcy *= inb; bcz *= inb;
            float ux = bx - ax, uy = by - ay, uz = bz - az;
            float nx = uy * bcz - uz * bcy;
            float ny = uz * bcx - ux * bcz;
            float nz = ux * bcy - uy * bcx;
            float inn = 1.f / sqrtf(nx * nx + ny * ny + nz * nz);
            nx *= inn; ny *= inn; nz *= inn;
            float mx = ny * bcz - nz * bcy;
            float my = nz * bcx - nx * bcz;
            float mz = nx * bcy - ny * bcx;
            float dx = bcx * d2x + mx * d2y + nx * d2z + cx;
            float dy = bcy * d2x + my * d2y + ny * d2z + cy;
            float dz = bcz * d2x + mz * d2y + nz * d2z + cz;
            int row = 3 + t * 3 + i;
            out[((size_t)row * 32 + b) * 3 + 0] = dx;
            out[((size_t)row * 32 + b) * 3 + 1] = dy;
            out[((size_t)row * 32 + b) * 3 + 2] = dz;
            ax = bx; ay = by; az = bz;
            bx = cx; by = cy; bz = cz;
            cx = dx; cy = dy; cz = dz;
        }
    }
}

extern "C" void kernel_launch(void* const* d_in, const int* in_sizes, int n_in,
                              void* d_out, int out_size, void* d_ws, size_t ws_size,
                              hipStream_t stream)
{
    const float* x     = (const float*)d_in[0];
    const float* wih0f = (const float*)d_in[1];
    const float* whh0f = (const float*)d_in[2];
    const float* b0f   = (const float*)d_in[3];
    const float* wih0b = (const float*)d_in[4];
    const float* whh0b = (const float*)d_in[5];
    const float* b0b   = (const float*)d_in[6];
    const float* wih1f = (const float*)d_in[7];
    const float* whh1f = (const float*)d_in[8];
    const float* b1f   = (const float*)d_in[9];
    const float* wih1b = (const float*)d_in[10];
    const float* whh1b = (const float*)d_in[11];
    const float* b1b   = (const float*)d_in[12];
    const float* linw  = (const float*)d_in[13];
    const float* linb  = (const float*)d_in[14];
    const float* alpha = (const float*)d_in[15];
    (void)in_sizes; (void)n_in; (void)out_size; (void)ws_size;

    char* ws = (char*)d_ws;
    size_t off = 0;
    auto alloc = [&](size_t bytes) -> void* {
        off = (off + 255) & ~(size_t)255;
        void* p = ws + off;
        off += bytes;
        return p;
    };
    const size_t XGC = (size_t)WSCAN * BATCH * G4;                        // 1,638,400 u16 (3.28 MB)
    u16* xT     = (u16*)alloc((size_t)T_LEN * BATCH * XPAD * 2);          // 2.1 MB
    u16* h1     = (u16*)alloc((size_t)T_LEN * BATCH * HSTR * 2);          // 54.5 MB
    u16* h2     = (u16*)alloc((size_t)T_LEN * BATCH * HSTR * 2);          // 54.5 MB
    u16* P2_0   = (u16*)alloc((size_t)2 * 50 * 2 * 27 * 2 * 64 * 8 * 2);  // 11.06 MB (both dirs)
    u16* P2_0f  = P2_0;
    u16* P2_0b  = P2_0 + (size_t)50 * 2 * 27 * 2 * 64 * 8;
    u16* P2_1f  = (u16*)alloc((size_t)50 * 2 * 25 * 2 * 64 * 8 * 2);      // 5.12 MB
    u16* P2_1b  = (u16*)alloc((size_t)50 * 2 * 25 * 2 * 64 * 8 * 2);
    u16* linwB  = (u16*)alloc((size_t)KCLS * 1600 * 2);
    float* bpk0f = (float*)alloc((size_t)G4 * 4);
    float* bpk0b = (float*)alloc((size_t)G4 * 4);
    u16* hzero  = (u16*)alloc((size_t)BATCH * HSTR * 2);
    float* c1f  = (float*)alloc((size_t)50 * 512 * 4);
    float* c1b  = (float*)alloc((size_t)50 * 512 * 4);
    u16* xgBbuf = (u16*)alloc(2 * XGC * 2);                               // 6.55 MB (two bwd chunks)
    unsigned* arrive = (unsigned*)alloc((size_t)NBLK * 32 * 4);
    // fwd xg double-buffer aliases the dead layer-0 weight packs (11.06 MB >= 6.55)
    u16* xgF0 = P2_0;
    u16* xgF1 = P2_0 + XGC;
    u16* xgB0 = xgBbuf;
    u16* xgB1 = xgBbuf + XGC;
    // epilogue buffers alias freed regions
    float* logitsF = (float*)P2_1f;   // 1.31 MB <= 5.12 MB (dead after scans)
    float* angF    = (float*)P2_1b;   // 0.20 MB

    // ---- prep ----
    k_zero16<<<dim3(32), dim3(256), 0, stream>>>(hzero, BATCH * HSTR);
    k_cvt<<<dim3(64), dim3(256), 0, stream>>>(linw, linwB, KCLS * 1600);
    k_xT<<<dim3(512), dim3(256), 0, stream>>>(x, xT);
    k_pack2<<<dim3(1024), dim3(256), 0, stream>>>(whh0f, wih0f, 27, DIN, P2_0f);
    k_pack2<<<dim3(1024), dim3(256), 0, stream>>>(whh0b, wih0b, 27, DIN, P2_0b);
    k_pack2<<<dim3(1024), dim3(256), 0, stream>>>(whh1f, nullptr, 25, 0, P2_1f);
    k_pack2<<<dim3(1024), dim3(256), 0, stream>>>(whh1b, nullptr, 25, 0, P2_1b);
    k_pack_bias<<<dim3(8), dim3(256), 0, stream>>>(b0f, bpk0f);
    k_pack_bias<<<dim3(8), dim3(256), 0, stream>>>(b0b, bpk0b);

    const size_t hstep = (size_t)BATCH * HSTR;

    // ---- layer 0: persistent scan (x-projection folded in) ----
    hipMemsetAsync(arrive, 0, (size_t)NBLK * 32 * 4, stream);
    scan_coop<<<dim3(NBLK), dim3(256), 0, stream>>>(
        xT, P2_0f, P2_0b, bpk0f, bpk0b, hzero, h1, arrive);

    // ---- layer 1: window-0 GEMM, then fused (scan w || gemm w+1) ----
    const int NW = T_LEN / WSCAN;   // 32
    hipMemsetAsync(arrive, 0, (size_t)NBLK * 32 * 4, stream);
    mfma_gemm<<<dim3(G4 / 128, WSCAN * BATCH / 128, 2), dim3(256), 0, stream>>>(
        h1, h1 + (size_t)(T_LEN - WSCAN) * hstep, HSTR,
        wih1f, wih1b, 1600, b1f, b1b,
        xgF0, xgB0, G4, G4, KPAD, 2, 1, 1);
    for (int w = 0; w < NW; ++w){
        const int s0 = w * WSCAN;
        u16* xgFc = (w & 1) ? xgF1 : xgF0;
        u16* xgBc = (w & 1) ? xgB1 : xgB0;
        u16* xgFn = (w & 1) ? xgF0 : xgF1;
        u16* xgBn = (w & 1) ? xgB0 : xgB1;
        const int have_next = (w + 1 < NW);
        const int t0f_n = (w + 1) * WSCAN;
        const int t0b_n = T_LEN - (w + 2) * WSCAN;
        scan_fused<<<dim3(2 * NBLK), dim3(256), 0, stream>>>(
            s0, xgFc, xgBc, P2_1f, P2_1b, hzero, h2,
            c1f, c1b, (w > 0) ? 1 : 0, arrive,
            have_next,
            h1 + (size_t)(have_next ? t0f_n : 0) * hstep,
            h1 + (size_t)(have_next ? t0b_n : 0) * hstep,
            wih1f, wih1b, b1f, b1b, xgFn, xgBn);
    }

    // ---- logits (N=20, fp32 out) ----
    mfma_gemm<<<dim3(1, T_LEN * BATCH / 128, 1), dim3(256), 0, stream>>>(
        h2, h2, HSTR, linwB, linwB, 1600, linb, linb,
        logitsF, logitsF, KCLS, KCLS, KPAD, 0, 0, 1);

    k_smax_ang<<<dim3(T_LEN), dim3(64), 0, stream>>>(logitsF, alpha, angF);
    k_coords<<<dim3(1), dim3(64), 0, stream>>>(angF, (float*)d_out);
}

// Round 15
// 7939.488 us; speedup vs baseline: 1.0465x; 1.0465x over previous
//
#include <hip/hip_runtime.h>

typedef unsigned short u16;
typedef _Float16 f16x8 __attribute__((ext_vector_type(8)));
typedef float f32x4 __attribute__((ext_vector_type(4)));

#define T_LEN 512
#define BATCH 32
#define DIN 42
#define XPAD 64
#define HID 800
#define G4 3200
#define KCLS 20
#define NBLK 100
#define WSCAN 32
#define HSTR 1664        // padded h row stride (u16): fwd 0..799, bwd 832..1631
#define BOFF 832         // bwd column offset (128B-aligned)
#define KPAD 1632        // logical GEMM K: fwd 0..799, hole 800..831 (zeros), bwd 832..1631 -> B row k-32

__device__ __forceinline__ u16 f2h(float f){
    union { _Float16 h; u16 u; } v; v.h = (_Float16)f; return v.u;
}
__device__ __forceinline__ float sigm(float x){ return 1.f / (1.f + __expf(-x)); }
__device__ __forceinline__ float tanh_(float x){ return 2.f / (1.f + __expf(-2.f * x)) - 1.f; }

// ---------------- prep kernels ----------------
__global__ void k_cvt(const float* __restrict__ s, u16* __restrict__ d, int n){
    for (int i = blockIdx.x * blockDim.x + threadIdx.x; i < n; i += gridDim.x * blockDim.x)
        d[i] = f2h(s[i]);
}
__global__ void k_zero16(u16* __restrict__ d, int n){
    for (int i = blockIdx.x * blockDim.x + threadIdx.x; i < n; i += gridDim.x * blockDim.x)
        d[i] = 0;
}
// x (B,T,42) fp32 -> xT (T,B,64) f16, zero-padded
__global__ void k_xT(const float* __restrict__ x, u16* __restrict__ xT){
    const int n = T_LEN * BATCH * XPAD;
    for (int i = blockIdx.x * blockDim.x + threadIdx.x; i < n; i += gridDim.x * blockDim.x){
        int t = i / (BATCH * XPAD);
        int rem = i % (BATCH * XPAD);
        int b = rem / XPAD, k = rem % XPAD;
        xT[i] = (k < DIN) ? f2h(x[((size_t)b * T_LEN + t) * DIN + k]) : (u16)0;
    }
}
// fused pack: z=0 whh0f+wih0f(nkk27), z=1 whh0b+wih0b(27), z=2 whh1f(25), z=3 whh1b(25)
__global__ void k_pack_all(const float* __restrict__ whh0f, const float* __restrict__ wih0f,
                           const float* __restrict__ whh0b, const float* __restrict__ wih0b,
                           const float* __restrict__ whh1f, const float* __restrict__ whh1b,
                           u16* __restrict__ P2_0f, u16* __restrict__ P2_0b,
                           u16* __restrict__ P2_1f, u16* __restrict__ P2_1b){
    const int z = blockIdx.z;
    const float* whh = (z == 0) ? whh0f : (z == 1) ? whh0b : (z == 2) ? whh1f : whh1b;
    const float* wih = (z == 0) ? wih0f : (z == 1) ? wih0b : nullptr;
    u16* P2 = (z == 0) ? P2_0f : (z == 1) ? P2_0b : (z == 2) ? P2_1f : P2_1b;
    const int nkk = (z < 2) ? 27 : 25;
    const int kin = (z < 2) ? DIN : 0;
    const int n_use = 50 * 2 * nkk * 2 * 64 * 8;
    for (int i = blockIdx.x * blockDim.x + threadIdx.x; i < n_use; i += gridDim.x * blockDim.x){
        int e = i & 7;
        int lane = (i >> 3) & 63;
        int which = (i >> 9) & 1;
        int r = i >> 10;
        int kk = r % nkk;
        int tn = r / nkk;
        int nh = tn & 1, tile = tn >> 1;
        int lr = lane & 15, kgrp = lane >> 4;
        int col = nh * 32 + which * 16 + lr;
        int gate = col >> 4, j = tile * 16 + (col & 15);
        float v;
        if (kk < 25){
            int k = kk * 32 + kgrp * 8 + e;
            v = whh[(size_t)(gate * 800 + j) * 800 + k];
        } else {
            int xk = (kk - 25) * 32 + kgrp * 8 + e;
            v = (xk < kin) ? wih[(size_t)(gate * 800 + j) * kin + xk] : 0.f;
        }
        P2[i] = f2h(v);
    }
}
// bias (3200) gate-major -> packed j*4+g fp32
__global__ void k_pack_bias(const float* __restrict__ b, float* __restrict__ bpk){
    for (int i = blockIdx.x * blockDim.x + threadIdx.x; i < G4; i += gridDim.x * blockDim.x){
        int g = i & 3, j = i >> 2;
        bpk[i] = b[g * 800 + j];
    }
}

// ---------------- MFMA GEMM (dual, z selects f/b): C[M,N] = A[M,K]*B[N,K]^T + bias ----
__global__ __launch_bounds__(256) void mfma_gemm(
    const u16* __restrict__ A0, const u16* __restrict__ A1, int lda,
    const void* __restrict__ B0_, const void* __restrict__ B1_, int ldb,
    const float* __restrict__ bias0, const float* __restrict__ bias1,
    void* __restrict__ C0, void* __restrict__ C1, int ldc,
    int M, int N, int K, int outmode, int b_is_f32, int khole)
{
    __shared__ u16 At[128 * 40];
    __shared__ u16 Bt[128 * 40];
    const int z = blockIdx.z;
    const u16* Ag = z ? A1 : A0;
    const void* Bg_ = z ? B1_ : B0_;
    const float* bias = z ? bias1 : bias0;
    void* Cg = z ? C1 : C0;
    const u16*   Bu = (const u16*)Bg_;
    const float* Bf = (const float*)Bg_;
    const int tid = threadIdx.x;
    const int lane = tid & 63, w = tid >> 6;
    const int wr = w >> 1, wc = w & 1;
    const int lr = lane & 15, kb8 = (lane >> 4) * 8;
    const int m0 = blockIdx.y * 128, n0 = blockIdx.x * 128;
    const int sr = tid >> 1, skg = (tid & 1) << 4;
    f32x4 acc[4][4] = {};
    const int KT = (K + 31) >> 5;
    for (int kt = 0; kt < KT; ++kt){
        const int k0 = kt << 5;
        __syncthreads();
        { // stage A
            size_t base = (size_t)(m0 + sr) * lda + k0 + skg;
            const f16x8* p = (const f16x8*)(Ag + base);
            *(f16x8*)&At[sr * 40 + skg] = p[0];
            *(f16x8*)&At[sr * 40 + skg + 8] = p[1];
        }
        { // stage B
            int rn = n0 + sr;
            const int hole = khole && (k0 == 800);
            const int kb = (khole && k0 >= 832) ? (k0 - 32) : k0;
            if (rn < N && !hole && b_is_f32){
                size_t base = (size_t)rn * ldb + kb + skg;
                const float4* p = (const float4*)(Bf + base);
                float4 q0 = p[0], q1 = p[1], q2 = p[2], q3 = p[3];
                f16x8 v0, v1;
                v0[0] = (_Float16)q0.x; v0[1] = (_Float16)q0.y; v0[2] = (_Float16)q0.z; v0[3] = (_Float16)q0.w;
                v0[4] = (_Float16)q1.x; v0[5] = (_Float16)q1.y; v0[6] = (_Float16)q1.z; v0[7] = (_Float16)q1.w;
                v1[0] = (_Float16)q2.x; v1[1] = (_Float16)q2.y; v1[2] = (_Float16)q2.z; v1[3] = (_Float16)q2.w;
                v1[4] = (_Float16)q3.x; v1[5] = (_Float16)q3.y; v1[6] = (_Float16)q3.z; v1[7] = (_Float16)q3.w;
                *(f16x8*)&Bt[sr * 40 + skg] = v0;
                *(f16x8*)&Bt[sr * 40 + skg + 8] = v1;
            } else if (rn < N && !hole){
                size_t base = (size_t)rn * ldb + kb + skg;
                const f16x8* p = (const f16x8*)(Bu + base);
                *(f16x8*)&Bt[sr * 40 + skg] = p[0];
                *(f16x8*)&Bt[sr * 40 + skg + 8] = p[1];
            } else {
                f16x8 zv = {};
                *(f16x8*)&Bt[sr * 40 + skg] = zv;
                *(f16x8*)&Bt[sr * 40 + skg + 8] = zv;
            }
        }
        __syncthreads();
        f16x8 af[4], bfr[4];
        #pragma unroll
        for (int mi = 0; mi < 4; ++mi)
            af[mi] = *(const f16x8*)&At[(wr * 64 + mi * 16 + lr) * 40 + kb8];
        #pragma unroll
        for (int ni = 0; ni < 4; ++ni)
            bfr[ni] = *(const f16x8*)&Bt[(wc * 64 + ni * 16 + lr) * 40 + kb8];
        #pragma unroll
        for (int mi = 0; mi < 4; ++mi)
            #pragma unroll
            for (int ni = 0; ni < 4; ++ni)
                acc[mi][ni] = __builtin_amdgcn_mfma_f32_16x16x32_f16(af[mi], bfr[ni], acc[mi][ni], 0, 0, 0);
    }
    #pragma unroll
    for (int mi = 0; mi < 4; ++mi){
        #pragma unroll
        for (int ni = 0; ni < 4; ++ni){
            int col = n0 + wc * 64 + ni * 16 + lr;
            if (col >= N) continue;
            float bs = bias ? bias[col] : 0.f;
            int pc = (outmode == 2) ? ((col % 800) * 4 + col / 800) : col;
            #pragma unroll
            for (int r = 0; r < 4; ++r){
                int row = m0 + wr * 64 + mi * 16 + ((lane >> 4) * 4 + r);
                float v = acc[mi][ni][r] + bs;
                if (outmode) ((u16*)Cg)[(size_t)row * ldc + pc] = f2h(v);
                else         ((float*)Cg)[(size_t)row * ldc + pc] = v;
            }
        }
    }
}

// ---------------- persistent bidirectional scan (R13 form + x-prefetch + all-wave poll) ----
__global__ __launch_bounds__(256, 1) void scan_coop(
    int nkk, int W, int s0,
    const u16* __restrict__ xTp,
    const u16* __restrict__ xgF, const u16* __restrict__ xgB,
    const u16* __restrict__ P2f, const u16* __restrict__ P2b,
    const float* __restrict__ bpkF, const float* __restrict__ bpkB,
    const u16* __restrict__ hzero, u16* __restrict__ h,
    float* __restrict__ cF, float* __restrict__ cB,
    int cload, int cstore, unsigned* __restrict__ arrive)
{
    __shared__ u16 wlds[2 * 27 * 2 * 64 * 8];   // 110,592 B max
    __shared__ float gLds[32][65];
    const int tid = threadIdx.x;
    const int dir = blockIdx.x & 1;
    const int tile = blockIdx.x >> 1;
    const u16* P2  = dir ? P2b : P2f;
    const u16* xg  = dir ? xgB : xgF;
    const float* bpk = dir ? bpkB : bpkF;
    float* cst = dir ? cB : cF;

    const int wcnt = 2 * nkk * 2 * 64 * 8;      // u16 per tile
    {
        const u16* src = P2 + (size_t)tile * wcnt;
        for (int i = tid * 8; i < wcnt; i += 256 * 8)
            *(f16x8*)&wlds[i] = *(const f16x8*)&src[i];
    }
    __syncthreads();

    const int lane = tid & 63, w = tid >> 6;
    const int mi = w >> 1, nh = w & 1;
    const int lr = lane & 15, kb8 = (lane >> 4) * 8;
    const int arow = mi * 16 + lr;
    const int b_ep = tid >> 3;            // batch sample for epilogue
    const int up   = (tid & 7) * 2;       // unit pair within tile
    const int j    = tile * 16 + up;

    float c0 = 0.f, c1 = 0.f;
    if (cload){
        c0 = cst[tile * 512 + tid * 2];
        c1 = cst[tile * 512 + tid * 2 + 1];
    }
    f32x4 bb0 = {}, bb1 = {};
    if (nkk == 27){
        bb0 = *(const f32x4*)(bpk + j * 4);
        bb1 = *(const f32x4*)(bpk + j * 4 + 4);
    }

    const size_t hstep = (size_t)BATCH * HSTR;

    // preload barrier-independent inputs for the first step
    f16x8 xa0 = {}, xa1 = {}, xv = {};
    {
        const int t0 = dir ? (T_LEN - 1 - s0) : s0;
        if (nkk == 27){
            const u16* xt = xTp + (size_t)t0 * (BATCH * XPAD) + arow * XPAD + kb8;
            xa0 = *(const f16x8*)(xt);
            xa1 = *(const f16x8*)(xt + 32);
        } else {
            const int qq = dir ? (W - 1) : 0;
            xv = *(const f16x8*)(xg + ((size_t)qq * BATCH + b_ep) * G4 + j * 4);
        }
    }

    for (int q = 0; q < W; ++q){
        const int s = s0 + q;
        const int t = dir ? (T_LEN - 1 - s) : s;
        const u16* hprev = (s == 0) ? (hzero + dir * BOFF)
                           : (h + (size_t)(dir ? t + 1 : t - 1) * hstep + dir * BOFF);

        // ---- load phase: h fragments (x inputs already in registers) ----
        const u16* hp = hprev + (size_t)arow * HSTR + kb8;
        f16x8 areg[25];
        #pragma unroll
        for (int kk = 0; kk < 25; ++kk)
            areg[kk] = *(const f16x8*)(hp + kk * 32);

        // ---- MFMA phase (weights from LDS), 4 accumulator chains ----
        f32x4 a0a = {}, a0b = {}, a1a = {}, a1b = {};
        #pragma unroll
        for (int kk = 0; kk < 24; kk += 2){
            f16x8 b0e = *(const f16x8*)&wlds[(size_t)((nh * nkk + kk) * 2 + 0) * 512 + lane * 8];
            f16x8 b1e = *(const f16x8*)&wlds[(size_t)((nh * nkk + kk) * 2 + 1) * 512 + lane * 8];
            f16x8 b0o = *(const f16x8*)&wlds[(size_t)((nh * nkk + kk + 1) * 2 + 0) * 512 + lane * 8];
            f16x8 b1o = *(const f16x8*)&wlds[(size_t)((nh * nkk + kk + 1) * 2 + 1) * 512 + lane * 8];
            a0a = __builtin_amdgcn_mfma_f32_16x16x32_f16(areg[kk],     b0e, a0a, 0, 0, 0);
            a1a = __builtin_amdgcn_mfma_f32_16x16x32_f16(areg[kk],     b1e, a1a, 0, 0, 0);
            a0b = __builtin_amdgcn_mfma_f32_16x16x32_f16(areg[kk + 1], b0o, a0b, 0, 0, 0);
            a1b = __builtin_amdgcn_mfma_f32_16x16x32_f16(areg[kk + 1], b1o, a1b, 0, 0, 0);
        }
        {
            f16x8 b0e = *(const f16x8*)&wlds[(size_t)((nh * nkk + 24) * 2 + 0) * 512 + lane * 8];
            f16x8 b1e = *(const f16x8*)&wlds[(size_t)((nh * nkk + 24) * 2 + 1) * 512 + lane * 8];
            a0a = __builtin_amdgcn_mfma_f32_16x16x32_f16(areg[24], b0e, a0a, 0, 0, 0);
            a1a = __builtin_amdgcn_mfma_f32_16x16x32_f16(areg[24], b1e, a1a, 0, 0, 0);
        }
        if (nkk == 27){
            f16x8 b0e = *(const f16x8*)&wlds[(size_t)((nh * nkk + 25) * 2 + 0) * 512 + lane * 8];
            f16x8 b1e = *(const f16x8*)&wlds[(size_t)((nh * nkk + 25) * 2 + 1) * 512 + lane * 8];
            a0b = __builtin_amdgcn_mfma_f32_16x16x32_f16(xa0, b0e, a0b, 0, 0, 0);
            a1b = __builtin_amdgcn_mfma_f32_16x16x32_f16(xa0, b1e, a1b, 0, 0, 0);
            f16x8 b0o = *(const f16x8*)&wlds[(size_t)((nh * nkk + 26) * 2 + 0) * 512 + lane * 8];
            f16x8 b1o = *(const f16x8*)&wlds[(size_t)((nh * nkk + 26) * 2 + 1) * 512 + lane * 8];
            a0a = __builtin_amdgcn_mfma_f32_16x16x32_f16(xa1, b0o, a0a, 0, 0, 0);
            a1a = __builtin_amdgcn_mfma_f32_16x16x32_f16(xa1, b1o, a1a, 0, 0, 0);
        }
        f32x4 acc0 = a0a + a0b;
        f32x4 acc1 = a1a + a1b;
        #pragma unroll
        for (int r = 0; r < 4; ++r){
            int b = mi * 16 + (lane >> 4) * 4 + r;
            gLds[b][nh * 32 + lr]      = acc0[r];
            gLds[b][nh * 32 + 16 + lr] = acc1[r];
        }
        __syncthreads();

        // ---- gate epilogue: 2 adjacent units per thread ----
        {
            float gi0, gf0, gg0, go0, gi1, gf1, gg1, go1;
            if (nkk == 27){
                gi0 = gLds[b_ep][up]          + bb0[0];
                gf0 = gLds[b_ep][16 + up]     + bb0[1];
                gg0 = gLds[b_ep][32 + up]     + bb0[2];
                go0 = gLds[b_ep][48 + up]     + bb0[3];
                gi1 = gLds[b_ep][up + 1]      + bb1[0];
                gf1 = gLds[b_ep][16 + up + 1] + bb1[1];
                gg1 = gLds[b_ep][32 + up + 1] + bb1[2];
                go1 = gLds[b_ep][48 + up + 1] + bb1[3];
            } else {
                gi0 = gLds[b_ep][up]          + (float)xv[0];
                gf0 = gLds[b_ep][16 + up]     + (float)xv[1];
                gg0 = gLds[b_ep][32 + up]     + (float)xv[2];
                go0 = gLds[b_ep][48 + up]     + (float)xv[3];
                gi1 = gLds[b_ep][up + 1]      + (float)xv[4];
                gf1 = gLds[b_ep][16 + up + 1] + (float)xv[5];
                gg1 = gLds[b_ep][32 + up + 1] + (float)xv[6];
                go1 = gLds[b_ep][48 + up + 1] + (float)xv[7];
            }
            float cn0 = sigm(gf0) * c0 + sigm(gi0) * tanh_(gg0);
            float cn1 = sigm(gf1) * c1 + sigm(gi1) * tanh_(gg1);
            c0 = cn0; c1 = cn1;
            union { unsigned u; _Float16 hh[2]; } pk;
            pk.hh[0] = (_Float16)(sigm(go0) * tanh_(cn0));
            pk.hh[1] = (_Float16)(sigm(go1) * tanh_(cn1));
            unsigned* dst = (unsigned*)(h + (size_t)t * hstep + dir * BOFF + (size_t)b_ep * HSTR + j);
            __hip_atomic_store(dst, pk.u, __ATOMIC_RELAXED, __HIP_MEMORY_SCOPE_AGENT);
        }

        if (q != W - 1){
            // prefetch next step's x inputs (barrier-independent) — latency hides under drain+poll
            const int sn = s + 1;
            if (nkk == 27){
                const int tn = dir ? (T_LEN - 1 - sn) : sn;
                const u16* xt = xTp + (size_t)tn * (BATCH * XPAD) + arow * XPAD + kb8;
                xa0 = *(const f16x8*)(xt);
                xa1 = *(const f16x8*)(xt + 32);
            } else {
                const int qq = dir ? (W - 1 - (q + 1)) : (q + 1);
                xv = *(const f16x8*)(xg + ((size_t)qq * BATCH + b_ep) * G4 + j * 4);
            }
            const unsigned tgt = (unsigned)(s + 1);
            __syncthreads();   // per-wave vmcnt(0): h-stores acked at LLC (prefetch also drains)
            if (tid == 0)
                __hip_atomic_store(arrive + (size_t)blockIdx.x * 32, tgt,
                                   __ATOMIC_RELAXED, __HIP_MEMORY_SCOPE_AGENT);
            // all-wave poll: each wave independently waits; no trailing __syncthreads needed
            {
                const unsigned* slot = arrive + (size_t)(((lane < 50) ? lane : 0) * 2 + dir) * 32;
                while (true){
                    unsigned v = __hip_atomic_load(slot, __ATOMIC_RELAXED, __HIP_MEMORY_SCOPE_AGENT);
                    if (__all((int)(v >= tgt))) break;
                    __builtin_amdgcn_s_sleep(1);
                }
            }
        }
    }
    if (cstore){
        cst[tile * 512 + tid * 2]     = c0;
        cst[tile * 512 + tid * 2 + 1] = c1;
    }
}

// ---------------- softmax over batch + angles ----------------
__global__ __launch_bounds__(64) void k_smax_ang(
    const float* __restrict__ logits, const float* __restrict__ alphabet,
    float* __restrict__ ang)
{
    int t = blockIdx.x;
    __shared__ float P[32][20];
    __shared__ float sA[20][3], cA[20][3];
    int tid = threadIdx.x;
    for (int idx = tid; idx < 32 * 20; idx += 64){
        int b = idx / 20, k = idx % 20;
        P[b][k] = logits[((size_t)t * 32 + b) * 20 + k];
    }
    for (int idx = tid; idx < 60; idx += 64){
        float al = alphabet[idx];
        sA[idx / 3][idx % 3] = sinf(al);
        cA[idx / 3][idx % 3] = cosf(al);
    }
    __syncthreads();
    if (tid < 20){
        float mx = -1e30f;
        for (int b = 0; b < 32; ++b) mx = fmaxf(mx, P[b][tid]);
        float s = 0.f;
        for (int b = 0; b < 32; ++b){ float e = __expf(P[b][tid] - mx); P[b][tid] = e; s += e; }
        float inv = 1.f / s;
        for (int b = 0; b < 32; ++b) P[b][tid] *= inv;
    }
    __syncthreads();
    if (tid < 32){
        float sx = 0, sy = 0, sz = 0, cx = 0, cy = 0, cz = 0;
        for (int k = 0; k < 20; ++k){
            float p = P[tid][k];
            sx += p * sA[k][0]; sy += p * sA[k][1]; sz += p * sA[k][2];
            cx += p * cA[k][0]; cy += p * cA[k][1]; cz += p * cA[k][2];
        }
        size_t base = ((size_t)t * 32 + tid) * 3;
        ang[base + 0] = atan2f(sx, cx);
        ang[base + 1] = atan2f(sy, cy);
        ang[base + 2] = atan2f(sz, cz);
    }
}

// ---------------- sequential coordinate chain ----------------
__global__ __launch_bounds__(64) void k_coords(const float* __restrict__ ang, float* __restrict__ out){
    int b = threadIdx.x;
    if (b >= 32) return;
    float ax = 0.f, ay = 0.f, az = 1.f;
    float bx = 0.f, by = 1.f, bz = 1.f;
    float cx = 1.f, cy = 1.f, cz = 1.f;
    out[(0 * 32 + b) * 3 + 0] = ax; out[(0 * 32 + b) * 3 + 1] = ay; out[(0 * 32 + b) * 3 + 2] = az;
    out[(1 * 32 + b) * 3 + 0] = bx; out[(1 * 32 + b) * 3 + 1] = by; out[(1 * 32 + b) * 3 + 2] = bz;
    out[(2 * 32 + b) * 3 + 0] = cx; out[(2 * 32 + b) * 3 + 1] = cy; out[(2 * 32 + b) * 3 + 2] = cz;
    const float rr[3] = {145.801f, 152.326f, 132.868f};
    const float ba[3] = {2.124f, 1.941f, 2.028f};
    float ct[3], st[3];
    #pragma unroll
    for (int i = 0; i < 3; ++i){ ct[i] = cosf(ba[i]); st[i] = sinf(ba[i]); }
    for (int t = 0; t < T_LEN; ++t){
        #pragma unroll
        for (int i = 0; i < 3; ++i){
            float p = ang[((size_t)t * 32 + b) * 3 + i];
            float d2x = -rr[i] * ct[i];
            float d2y = rr[i] * cosf(p) * st[i];
            float d2z = rr[i] * sinf(p) * st[i];
            float bcx = cx - bx, bcy = cy - by, bcz = cz - bz;
            float inb = 1.f / sqrtf(bcx * bcx + bcy * bcy + bcz * bcz);
            bcx *= inb; bcy *= inb; bcz *= inb;
            float ux = bx - ax, uy = by - ay, uz = bz - az;
            float nx = uy * bcz - uz * bcy;
            float ny = uz * bcx - ux * bcz;
            float nz = ux * bcy - uy * bcx;
            float inn = 1.f / sqrtf(nx * nx + ny * ny + nz * nz);
            nx *= inn; ny *= inn; nz *= inn;
            float mx = ny * bcz - nz * bcy;
            float my = nz * bcx - nx * bcz;
            float mz = nx * bcy - ny * bcx;
            float dx = bcx * d2x + mx * d2y + nx * d2z + cx;
            float dy = bcy * d2x + my * d2y + ny * d2z + cy;
            float dz = bcz * d2x + mz * d2y + nz * d2z + cz;
            int row = 3 + t * 3 + i;
            out[((size_t)row * 32 + b) * 3 + 0] = dx;
            out[((size_t)row * 32 + b) * 3 + 1] = dy;
            out[((size_t)row * 32 + b) * 3 + 2] = dz;
            ax = bx; ay = by; az = bz;
            bx = cx; by = cy; bz = cz;
            cx = dx; cy = dy; cz = dz;
        }
    }
}

extern "C" void kernel_launch(void* const* d_in, const int* in_sizes, int n_in,
                              void* d_out, int out_size, void* d_ws, size_t ws_size,
                              hipStream_t stream)
{
    const float* x     = (const float*)d_in[0];
    const float* wih0f = (const float*)d_in[1];
    const float* whh0f = (const float*)d_in[2];
    const float* b0f   = (const float*)d_in[3];
    const float* wih0b = (const float*)d_in[4];
    const float* whh0b = (const float*)d_in[5];
    const float* b0b   = (const float*)d_in[6];
    const float* wih1f = (const float*)d_in[7];
    const float* whh1f = (const float*)d_in[8];
    const float* b1f   = (const float*)d_in[9];
    const float* wih1b = (const float*)d_in[10];
    const float* whh1b = (const float*)d_in[11];
    const float* b1b   = (const float*)d_in[12];
    const float* linw  = (const float*)d_in[13];
    const float* linb  = (const float*)d_in[14];
    const float* alpha = (const float*)d_in[15];
    (void)in_sizes; (void)n_in; (void)out_size; (void)ws_size;

    char* ws = (char*)d_ws;
    size_t off = 0;
    auto alloc = [&](size_t bytes) -> void* {
        off = (off + 255) & ~(size_t)255;
        void* p = ws + off;
        off += bytes;
        return p;
    };
    u16* xT     = (u16*)alloc((size_t)T_LEN * BATCH * XPAD * 2);          // 2.1 MB
    u16* h1     = (u16*)alloc((size_t)T_LEN * BATCH * HSTR * 2);          // 54.5 MB
    u16* h2     = (u16*)alloc((size_t)T_LEN * BATCH * HSTR * 2);          // 54.5 MB
    u16* P2_0   = (u16*)alloc((size_t)2 * 50 * 2 * 27 * 2 * 64 * 8 * 2);  // 11.06 MB (both dirs)
    u16* P2_0f  = P2_0;
    u16* P2_0b  = P2_0 + (size_t)50 * 2 * 27 * 2 * 64 * 8;
    u16* P2_1f  = (u16*)alloc((size_t)50 * 2 * 25 * 2 * 64 * 8 * 2);      // 5.12 MB
    u16* P2_1b  = (u16*)alloc((size_t)50 * 2 * 25 * 2 * 64 * 8 * 2);
    u16* linwB  = (u16*)alloc((size_t)KCLS * 1600 * 2);
    float* bpk0f = (float*)alloc((size_t)G4 * 4);
    float* bpk0b = (float*)alloc((size_t)G4 * 4);
    u16* hzero  = (u16*)alloc((size_t)BATCH * HSTR * 2);
    float* c1f  = (float*)alloc((size_t)50 * 512 * 4);
    float* c1b  = (float*)alloc((size_t)50 * 512 * 4);
    u16* xgBc   = (u16*)alloc((size_t)WSCAN * BATCH * G4 * 2);            // 6.55 MB
    unsigned* arrive = (unsigned*)alloc((size_t)NBLK * 32 * 4);           // 12.8 KB
    // xgFc aliases the layer-0 weight packs (dead after layer-0 scan): 6.55 MB <= 11.06 MB
    u16* xgFc = P2_0;
    // epilogue buffers alias freed xg chunks
    float* logitsF = (float*)xgFc;   // 1.31 MB <= 6.55 MB
    float* angF    = (float*)xgBc;   // 0.20 MB

    // ---- prep ----
    k_zero16<<<dim3(32), dim3(256), 0, stream>>>(hzero, BATCH * HSTR);
    k_cvt<<<dim3(64), dim3(256), 0, stream>>>(linw, linwB, KCLS * 1600);
    k_xT<<<dim3(512), dim3(256), 0, stream>>>(x, xT);
    k_pack_all<<<dim3(512, 1, 4), dim3(256), 0, stream>>>(
        whh0f, wih0f, whh0b, wih0b, whh1f, whh1b, P2_0f, P2_0b, P2_1f, P2_1b);
    k_pack_bias<<<dim3(8), dim3(256), 0, stream>>>(b0f, bpk0f);
    k_pack_bias<<<dim3(8), dim3(256), 0, stream>>>(b0b, bpk0b);

    const size_t hstep = (size_t)BATCH * HSTR;

    // ---- layer 0: persistent scan (x-projection folded in) ----
    hipMemsetAsync(arrive, 0, (size_t)NBLK * 32 * 4, stream);
    scan_coop<<<dim3(NBLK), dim3(256), 0, stream>>>(
        27, T_LEN, 0,
        xT, nullptr, nullptr,
        P2_0f, P2_0b, bpk0f, bpk0b,
        hzero, h1, nullptr, nullptr, 0, 0, arrive);

    // ---- layer 1: windowed dual GEMM + persistent scan per window ----
    hipMemsetAsync(arrive, 0, (size_t)NBLK * 32 * 4, stream);  // step values monotone across windows
    for (int w = 0; w < T_LEN / WSCAN; ++w){
        const int s0  = w * WSCAN;
        const int t0f = s0;
        const int t0b = T_LEN - (w + 1) * WSCAN;
        mfma_gemm<<<dim3(G4 / 128, WSCAN * BATCH / 128, 2), dim3(256), 0, stream>>>(
            h1 + (size_t)t0f * hstep, h1 + (size_t)t0b * hstep, HSTR,
            wih1f, wih1b, 1600, b1f, b1b,
            xgFc, xgBc, G4, WSCAN * BATCH, G4, KPAD, 2, 1, 1);
        scan_coop<<<dim3(NBLK), dim3(256), 0, stream>>>(
            25, WSCAN, s0,
            nullptr, xgFc, xgBc,
            P2_1f, P2_1b, nullptr, nullptr,
            hzero, h2, c1f, c1b, (w > 0) ? 1 : 0, 1, arrive);
    }

    // ---- logits (N=20, fp32 out) ----
    mfma_gemm<<<dim3(1, T_LEN * BATCH / 128, 1), dim3(256), 0, stream>>>(
        h2, h2, HSTR, linwB, linwB, 1600, linb, linb,
        logitsF, logitsF, KCLS, T_LEN * BATCH, KCLS, KPAD, 0, 0, 1);

    k_smax_ang<<<dim3(T_LEN), dim3(64), 0, stream>>>(logitsF, alpha, angF);
    k_coords<<<dim3(1), dim3(64), 0, stream>>>(angF, (float*)d_out);
}

// Round 16
// 7011.923 us; speedup vs baseline: 1.1850x; 1.1323x over previous
//
#include <hip/hip_runtime.h>

typedef unsigned short u16;
typedef _Float16 f16x8 __attribute__((ext_vector_type(8)));
typedef float f32x4 __attribute__((ext_vector_type(4)));

#define T_LEN 512
#define BATCH 32
#define DIN 42
#define XPAD 64
#define HID 800
#define G4 3200
#define KCLS 20
#define NBLK 100
#define WSCAN 32
#define HSTR 1664        // padded h row stride (u16): fwd 0..799, bwd 832..1631
#define BOFF 832         // bwd column offset (128B-aligned)
#define KPAD 1632        // logical GEMM K: fwd 0..799, hole 800..831 (zeros), bwd 832..1631 -> B row k-32

__device__ __forceinline__ u16 f2h(float f){
    union { _Float16 h; u16 u; } v; v.h = (_Float16)f; return v.u;
}
__device__ __forceinline__ float sigm(float x){ return 1.f / (1.f + __expf(-x)); }
__device__ __forceinline__ float tanh_(float x){ return 2.f / (1.f + __expf(-2.f * x)) - 1.f; }

// ---------------- prep kernels ----------------
__global__ void k_cvt(const float* __restrict__ s, u16* __restrict__ d, int n){
    for (int i = blockIdx.x * blockDim.x + threadIdx.x; i < n; i += gridDim.x * blockDim.x)
        d[i] = f2h(s[i]);
}
__global__ void k_zero16(u16* __restrict__ d, int n){
    for (int i = blockIdx.x * blockDim.x + threadIdx.x; i < n; i += gridDim.x * blockDim.x)
        d[i] = 0;
}
// x (B,T,42) fp32 -> xT (T,B,64) f16, zero-padded
__global__ void k_xT(const float* __restrict__ x, u16* __restrict__ xT){
    const int n = T_LEN * BATCH * XPAD;
    for (int i = blockIdx.x * blockDim.x + threadIdx.x; i < n; i += gridDim.x * blockDim.x){
        int t = i / (BATCH * XPAD);
        int rem = i % (BATCH * XPAD);
        int b = rem / XPAD, k = rem % XPAD;
        xT[i] = (k < DIN) ? f2h(x[((size_t)b * T_LEN + t) * DIN + k]) : (u16)0;
    }
}
// fused pack: z=0 whh0f+wih0f(nkk27), z=1 whh0b+wih0b(27), z=2 whh1f(25), z=3 whh1b(25)
__global__ void k_pack_all(const float* __restrict__ whh0f, const float* __restrict__ wih0f,
                           const float* __restrict__ whh0b, const float* __restrict__ wih0b,
                           const float* __restrict__ whh1f, const float* __restrict__ whh1b,
                           u16* __restrict__ P2_0f, u16* __restrict__ P2_0b,
                           u16* __restrict__ P2_1f, u16* __restrict__ P2_1b){
    const int z = blockIdx.z;
    const float* whh = (z == 0) ? whh0f : (z == 1) ? whh0b : (z == 2) ? whh1f : whh1b;
    const float* wih = (z == 0) ? wih0f : (z == 1) ? wih0b : nullptr;
    u16* P2 = (z == 0) ? P2_0f : (z == 1) ? P2_0b : (z == 2) ? P2_1f : P2_1b;
    const int nkk = (z < 2) ? 27 : 25;
    const int kin = (z < 2) ? DIN : 0;
    const int n_use = 50 * 2 * nkk * 2 * 64 * 8;
    for (int i = blockIdx.x * blockDim.x + threadIdx.x; i < n_use; i += gridDim.x * blockDim.x){
        int e = i & 7;
        int lane = (i >> 3) & 63;
        int which = (i >> 9) & 1;
        int r = i >> 10;
        int kk = r % nkk;
        int tn = r / nkk;
        int nh = tn & 1, tile = tn >> 1;
        int lr = lane & 15, kgrp = lane >> 4;
        int col = nh * 32 + which * 16 + lr;
        int gate = col >> 4, j = tile * 16 + (col & 15);
        float v;
        if (kk < 25){
            int k = kk * 32 + kgrp * 8 + e;
            v = whh[(size_t)(gate * 800 + j) * 800 + k];
        } else {
            int xk = (kk - 25) * 32 + kgrp * 8 + e;
            v = (xk < kin) ? wih[(size_t)(gate * 800 + j) * kin + xk] : 0.f;
        }
        P2[i] = f2h(v);
    }
}
// bias (3200) gate-major -> packed j*4+g fp32
__global__ void k_pack_bias(const float* __restrict__ b, float* __restrict__ bpk){
    for (int i = blockIdx.x * blockDim.x + threadIdx.x; i < G4; i += gridDim.x * blockDim.x){
        int g = i & 3, j = i >> 2;
        bpk[i] = b[g * 800 + j];
    }
}

// ---------------- MFMA GEMM (dual, z selects f/b): C[M,N] = A[M,K]*B[N,K]^T + bias ----
__global__ __launch_bounds__(256) void mfma_gemm(
    const u16* __restrict__ A0, const u16* __restrict__ A1, int lda,
    const void* __restrict__ B0_, const void* __restrict__ B1_, int ldb,
    const float* __restrict__ bias0, const float* __restrict__ bias1,
    void* __restrict__ C0, void* __restrict__ C1, int ldc,
    int M, int N, int K, int outmode, int b_is_f32, int khole)
{
    __shared__ u16 At[128 * 40];
    __shared__ u16 Bt[128 * 40];
    const int z = blockIdx.z;
    const u16* Ag = z ? A1 : A0;
    const void* Bg_ = z ? B1_ : B0_;
    const float* bias = z ? bias1 : bias0;
    void* Cg = z ? C1 : C0;
    const u16*   Bu = (const u16*)Bg_;
    const float* Bf = (const float*)Bg_;
    const int tid = threadIdx.x;
    const int lane = tid & 63, w = tid >> 6;
    const int wr = w >> 1, wc = w & 1;
    const int lr = lane & 15, kb8 = (lane >> 4) * 8;
    const int m0 = blockIdx.y * 128, n0 = blockIdx.x * 128;
    const int sr = tid >> 1, skg = (tid & 1) << 4;
    f32x4 acc[4][4] = {};
    const int KT = (K + 31) >> 5;
    for (int kt = 0; kt < KT; ++kt){
        const int k0 = kt << 5;
        __syncthreads();
        { // stage A
            size_t base = (size_t)(m0 + sr) * lda + k0 + skg;
            const f16x8* p = (const f16x8*)(Ag + base);
            *(f16x8*)&At[sr * 40 + skg] = p[0];
            *(f16x8*)&At[sr * 40 + skg + 8] = p[1];
        }
        { // stage B
            int rn = n0 + sr;
            const int hole = khole && (k0 == 800);
            const int kb = (khole && k0 >= 832) ? (k0 - 32) : k0;
            if (rn < N && !hole && b_is_f32){
                size_t base = (size_t)rn * ldb + kb + skg;
                const float4* p = (const float4*)(Bf + base);
                float4 q0 = p[0], q1 = p[1], q2 = p[2], q3 = p[3];
                f16x8 v0, v1;
                v0[0] = (_Float16)q0.x; v0[1] = (_Float16)q0.y; v0[2] = (_Float16)q0.z; v0[3] = (_Float16)q0.w;
                v0[4] = (_Float16)q1.x; v0[5] = (_Float16)q1.y; v0[6] = (_Float16)q1.z; v0[7] = (_Float16)q1.w;
                v1[0] = (_Float16)q2.x; v1[1] = (_Float16)q2.y; v1[2] = (_Float16)q2.z; v1[3] = (_Float16)q2.w;
                v1[4] = (_Float16)q3.x; v1[5] = (_Float16)q3.y; v1[6] = (_Float16)q3.z; v1[7] = (_Float16)q3.w;
                *(f16x8*)&Bt[sr * 40 + skg] = v0;
                *(f16x8*)&Bt[sr * 40 + skg + 8] = v1;
            } else if (rn < N && !hole){
                size_t base = (size_t)rn * ldb + kb + skg;
                const f16x8* p = (const f16x8*)(Bu + base);
                *(f16x8*)&Bt[sr * 40 + skg] = p[0];
                *(f16x8*)&Bt[sr * 40 + skg + 8] = p[1];
            } else {
                f16x8 zv = {};
                *(f16x8*)&Bt[sr * 40 + skg] = zv;
                *(f16x8*)&Bt[sr * 40 + skg + 8] = zv;
            }
        }
        __syncthreads();
        f16x8 af[4], bfr[4];
        #pragma unroll
        for (int mi = 0; mi < 4; ++mi)
            af[mi] = *(const f16x8*)&At[(wr * 64 + mi * 16 + lr) * 40 + kb8];
        #pragma unroll
        for (int ni = 0; ni < 4; ++ni)
            bfr[ni] = *(const f16x8*)&Bt[(wc * 64 + ni * 16 + lr) * 40 + kb8];
        #pragma unroll
        for (int mi = 0; mi < 4; ++mi)
            #pragma unroll
            for (int ni = 0; ni < 4; ++ni)
                acc[mi][ni] = __builtin_amdgcn_mfma_f32_16x16x32_f16(af[mi], bfr[ni], acc[mi][ni], 0, 0, 0);
    }
    #pragma unroll
    for (int mi = 0; mi < 4; ++mi){
        #pragma unroll
        for (int ni = 0; ni < 4; ++ni){
            int col = n0 + wc * 64 + ni * 16 + lr;
            if (col >= N) continue;
            float bs = bias ? bias[col] : 0.f;
            int pc = (outmode == 2) ? ((col % 800) * 4 + col / 800) : col;
            #pragma unroll
            for (int r = 0; r < 4; ++r){
                int row = m0 + wr * 64 + mi * 16 + ((lane >> 4) * 4 + r);
                float v = acc[mi][ni][r] + bs;
                if (outmode) ((u16*)Cg)[(size_t)row * ldc + pc] = f2h(v);
                else         ((float*)Cg)[(size_t)row * ldc + pc] = v;
            }
        }
    }
}

// ---------------- persistent bidirectional scan (R13-proven form, reverted exactly) ----------
__global__ __launch_bounds__(256, 1) void scan_coop(
    int nkk, int W, int s0,
    const u16* __restrict__ xTp,
    const u16* __restrict__ xgF, const u16* __restrict__ xgB,
    const u16* __restrict__ P2f, const u16* __restrict__ P2b,
    const float* __restrict__ bpkF, const float* __restrict__ bpkB,
    const u16* __restrict__ hzero, u16* __restrict__ h,
    float* __restrict__ cF, float* __restrict__ cB,
    int cload, int cstore, unsigned* __restrict__ arrive)
{
    __shared__ u16 wlds[2 * 27 * 2 * 64 * 8];   // 110,592 B max
    __shared__ float gLds[32][65];
    const int tid = threadIdx.x;
    const int dir = blockIdx.x & 1;
    const int tile = blockIdx.x >> 1;
    const u16* P2  = dir ? P2b : P2f;
    const u16* xg  = dir ? xgB : xgF;
    const float* bpk = dir ? bpkB : bpkF;
    float* cst = dir ? cB : cF;

    const int wcnt = 2 * nkk * 2 * 64 * 8;      // u16 per tile
    {
        const u16* src = P2 + (size_t)tile * wcnt;
        for (int i = tid * 8; i < wcnt; i += 256 * 8)
            *(f16x8*)&wlds[i] = *(const f16x8*)&src[i];
    }
    __syncthreads();

    const int lane = tid & 63, w = tid >> 6;
    const int mi = w >> 1, nh = w & 1;
    const int lr = lane & 15, kb8 = (lane >> 4) * 8;
    const int arow = mi * 16 + lr;
    const int b_ep = tid >> 3;            // batch sample for epilogue
    const int up   = (tid & 7) * 2;       // unit pair within tile
    const int j    = tile * 16 + up;

    float c0 = 0.f, c1 = 0.f;
    if (cload){
        c0 = cst[tile * 512 + tid * 2];
        c1 = cst[tile * 512 + tid * 2 + 1];
    }
    f32x4 bb0 = {}, bb1 = {};
    if (nkk == 27){
        bb0 = *(const f32x4*)(bpk + j * 4);
        bb1 = *(const f32x4*)(bpk + j * 4 + 4);
    }

    const size_t hstep = (size_t)BATCH * HSTR;

    for (int q = 0; q < W; ++q){
        const int s = s0 + q;
        const int t = dir ? (T_LEN - 1 - s) : s;
        const u16* hprev = (s == 0) ? (hzero + dir * BOFF)
                           : (h + (size_t)(dir ? t + 1 : t - 1) * hstep + dir * BOFF);

        // ---- load phase: h fragments + per-step inputs in flight together ----
        const u16* hp = hprev + (size_t)arow * HSTR + kb8;
        f16x8 areg[25];
        #pragma unroll
        for (int kk = 0; kk < 25; ++kk)
            areg[kk] = *(const f16x8*)(hp + kk * 32);
        f16x8 xa0 = {}, xa1 = {}, xv = {};
        if (nkk == 27){
            const u16* xt = xTp + (size_t)t * (BATCH * XPAD) + arow * XPAD + kb8;
            xa0 = *(const f16x8*)(xt);
            xa1 = *(const f16x8*)(xt + 32);
        } else {
            const int qq = dir ? (W - 1 - q) : q;
            xv = *(const f16x8*)(xg + ((size_t)qq * BATCH + b_ep) * G4 + j * 4);
        }

        // ---- MFMA phase (weights from LDS), 4 accumulator chains ----
        f32x4 a0a = {}, a0b = {}, a1a = {}, a1b = {};
        #pragma unroll
        for (int kk = 0; kk < 24; kk += 2){
            f16x8 b0e = *(const f16x8*)&wlds[(size_t)((nh * nkk + kk) * 2 + 0) * 512 + lane * 8];
            f16x8 b1e = *(const f16x8*)&wlds[(size_t)((nh * nkk + kk) * 2 + 1) * 512 + lane * 8];
            f16x8 b0o = *(const f16x8*)&wlds[(size_t)((nh * nkk + kk + 1) * 2 + 0) * 512 + lane * 8];
            f16x8 b1o = *(const f16x8*)&wlds[(size_t)((nh * nkk + kk + 1) * 2 + 1) * 512 + lane * 8];
            a0a = __builtin_amdgcn_mfma_f32_16x16x32_f16(areg[kk],     b0e, a0a, 0, 0, 0);
            a1a = __builtin_amdgcn_mfma_f32_16x16x32_f16(areg[kk],     b1e, a1a, 0, 0, 0);
            a0b = __builtin_amdgcn_mfma_f32_16x16x32_f16(areg[kk + 1], b0o, a0b, 0, 0, 0);
            a1b = __builtin_amdgcn_mfma_f32_16x16x32_f16(areg[kk + 1], b1o, a1b, 0, 0, 0);
        }
        {
            f16x8 b0e = *(const f16x8*)&wlds[(size_t)((nh * nkk + 24) * 2 + 0) * 512 + lane * 8];
            f16x8 b1e = *(const f16x8*)&wlds[(size_t)((nh * nkk + 24) * 2 + 1) * 512 + lane * 8];
            a0a = __builtin_amdgcn_mfma_f32_16x16x32_f16(areg[24], b0e, a0a, 0, 0, 0);
            a1a = __builtin_amdgcn_mfma_f32_16x16x32_f16(areg[24], b1e, a1a, 0, 0, 0);
        }
        if (nkk == 27){
            f16x8 b0e = *(const f16x8*)&wlds[(size_t)((nh * nkk + 25) * 2 + 0) * 512 + lane * 8];
            f16x8 b1e = *(const f16x8*)&wlds[(size_t)((nh * nkk + 25) * 2 + 1) * 512 + lane * 8];
            a0b = __builtin_amdgcn_mfma_f32_16x16x32_f16(xa0, b0e, a0b, 0, 0, 0);
            a1b = __builtin_amdgcn_mfma_f32_16x16x32_f16(xa0, b1e, a1b, 0, 0, 0);
            f16x8 b0o = *(const f16x8*)&wlds[(size_t)((nh * nkk + 26) * 2 + 0) * 512 + lane * 8];
            f16x8 b1o = *(const f16x8*)&wlds[(size_t)((nh * nkk + 26) * 2 + 1) * 512 + lane * 8];
            a0a = __builtin_amdgcn_mfma_f32_16x16x32_f16(xa1, b0o, a0a, 0, 0, 0);
            a1a = __builtin_amdgcn_mfma_f32_16x16x32_f16(xa1, b1o, a1a, 0, 0, 0);
        }
        f32x4 acc0 = a0a + a0b;
        f32x4 acc1 = a1a + a1b;
        #pragma unroll
        for (int r = 0; r < 4; ++r){
            int b = mi * 16 + (lane >> 4) * 4 + r;
            gLds[b][nh * 32 + lr]      = acc0[r];
            gLds[b][nh * 32 + 16 + lr] = acc1[r];
        }
        __syncthreads();

        // ---- gate epilogue: 2 adjacent units per thread ----
        {
            float gi0, gf0, gg0, go0, gi1, gf1, gg1, go1;
            if (nkk == 27){
                gi0 = gLds[b_ep][up]          + bb0[0];
                gf0 = gLds[b_ep][16 + up]     + bb0[1];
                gg0 = gLds[b_ep][32 + up]     + bb0[2];
                go0 = gLds[b_ep][48 + up]     + bb0[3];
                gi1 = gLds[b_ep][up + 1]      + bb1[0];
                gf1 = gLds[b_ep][16 + up + 1] + bb1[1];
                gg1 = gLds[b_ep][32 + up + 1] + bb1[2];
                go1 = gLds[b_ep][48 + up + 1] + bb1[3];
            } else {
                gi0 = gLds[b_ep][up]          + (float)xv[0];
                gf0 = gLds[b_ep][16 + up]     + (float)xv[1];
                gg0 = gLds[b_ep][32 + up]     + (float)xv[2];
                go0 = gLds[b_ep][48 + up]     + (float)xv[3];
                gi1 = gLds[b_ep][up + 1]      + (float)xv[4];
                gf1 = gLds[b_ep][16 + up + 1] + (float)xv[5];
                gg1 = gLds[b_ep][32 + up + 1] + (float)xv[6];
                go1 = gLds[b_ep][48 + up + 1] + (float)xv[7];
            }
            float cn0 = sigm(gf0) * c0 + sigm(gi0) * tanh_(gg0);
            float cn1 = sigm(gf1) * c1 + sigm(gi1) * tanh_(gg1);
            c0 = cn0; c1 = cn1;
            union { unsigned u; _Float16 hh[2]; } pk;
            pk.hh[0] = (_Float16)(sigm(go0) * tanh_(cn0));
            pk.hh[1] = (_Float16)(sigm(go1) * tanh_(cn1));
            unsigned* dst = (unsigned*)(h + (size_t)t * hstep + dir * BOFF + (size_t)b_ep * HSTR + j);
            __hip_atomic_store(dst, pk.u, __ATOMIC_RELAXED, __HIP_MEMORY_SCOPE_AGENT);
        }

        if (q != W - 1){
            const unsigned tgt = (unsigned)(s + 1);
            __syncthreads();   // per-wave vmcnt(0): h-stores acked at LLC
            if (tid == 0)
                __hip_atomic_store(arrive + (size_t)blockIdx.x * 32, tgt,
                                   __ATOMIC_RELAXED, __HIP_MEMORY_SCOPE_AGENT);
            if (tid < 64){
                const unsigned* slot = arrive + (size_t)(((tid < 50) ? tid : 0) * 2 + dir) * 32;
                while (true){
                    unsigned v = __hip_atomic_load(slot, __ATOMIC_RELAXED, __HIP_MEMORY_SCOPE_AGENT);
                    if (__all((int)(v >= tgt))) break;
                    __builtin_amdgcn_s_sleep(1);
                }
            }
            __syncthreads();
        }
    }
    if (cstore){
        cst[tile * 512 + tid * 2]     = c0;
        cst[tile * 512 + tid * 2 + 1] = c1;
    }
}

// ---------------- softmax over batch + torsion (cos,sin) ----------------
// stores cs/sn directly: cos(atan2(s,c)) = c/hyp, sin(atan2(s,c)) = s/hyp
__global__ __launch_bounds__(64) void k_smax_ang(
    const float* __restrict__ logits, const float* __restrict__ alphabet,
    float* __restrict__ csn)
{
    int t = blockIdx.x;
    __shared__ float P[32][20];
    __shared__ float sA[20][3], cA[20][3];
    int tid = threadIdx.x;
    for (int idx = tid; idx < 32 * 20; idx += 64){
        int b = idx / 20, k = idx % 20;
        P[b][k] = logits[((size_t)t * 32 + b) * 20 + k];
    }
    for (int idx = tid; idx < 60; idx += 64){
        float al = alphabet[idx];
        sA[idx / 3][idx % 3] = sinf(al);
        cA[idx / 3][idx % 3] = cosf(al);
    }
    __syncthreads();
    if (tid < 20){
        float mx = -1e30f;
        for (int b = 0; b < 32; ++b) mx = fmaxf(mx, P[b][tid]);
        float s = 0.f;
        for (int b = 0; b < 32; ++b){ float e = __expf(P[b][tid] - mx); P[b][tid] = e; s += e; }
        float inv = 1.f / s;
        for (int b = 0; b < 32; ++b) P[b][tid] *= inv;
    }
    __syncthreads();
    if (tid < 32){
        float sx = 0, sy = 0, sz = 0, cx = 0, cy = 0, cz = 0;
        for (int k = 0; k < 20; ++k){
            float p = P[tid][k];
            sx += p * sA[k][0]; sy += p * sA[k][1]; sz += p * sA[k][2];
            cx += p * cA[k][0]; cy += p * cA[k][1]; cz += p * cA[k][2];
        }
        size_t base = ((size_t)t * 32 + tid) * 6;
        float h0 = rsqrtf(sx * sx + cx * cx);
        float h1v = rsqrtf(sy * sy + cy * cy);
        float h2v = rsqrtf(sz * sz + cz * cz);
        csn[base + 0] = cx * h0;  csn[base + 1] = sx * h0;
        csn[base + 2] = cy * h1v; csn[base + 3] = sy * h1v;
        csn[base + 4] = cz * h2v; csn[base + 5] = sz * h2v;
    }
}

// ---------------- sequential coordinate chain (trig-free) ----------------
__global__ __launch_bounds__(64) void k_coords(const float* __restrict__ csn, float* __restrict__ out){
    int b = threadIdx.x;
    if (b >= 32) return;
    float ax = 0.f, ay = 0.f, az = 1.f;
    float bx = 0.f, by = 1.f, bz = 1.f;
    float cx = 1.f, cy = 1.f, cz = 1.f;
    out[(0 * 32 + b) * 3 + 0] = ax; out[(0 * 32 + b) * 3 + 1] = ay; out[(0 * 32 + b) * 3 + 2] = az;
    out[(1 * 32 + b) * 3 + 0] = bx; out[(1 * 32 + b) * 3 + 1] = by; out[(1 * 32 + b) * 3 + 2] = bz;
    out[(2 * 32 + b) * 3 + 0] = cx; out[(2 * 32 + b) * 3 + 1] = cy; out[(2 * 32 + b) * 3 + 2] = cz;
    const float rr[3] = {145.801f, 152.326f, 132.868f};
    const float ba[3] = {2.124f, 1.941f, 2.028f};
    float d2xc[3], st[3];
    #pragma unroll
    for (int i = 0; i < 3; ++i){ d2xc[i] = -rr[i] * cosf(ba[i]); st[i] = rr[i] * sinf(ba[i]); }
    for (int t = 0; t < T_LEN; ++t){
        #pragma unroll
        for (int i = 0; i < 3; ++i){
            size_t base = ((size_t)t * 32 + b) * 6 + i * 2;
            float cp = csn[base + 0], sp = csn[base + 1];
            float d2x = d2xc[i];
            float d2y = cp * st[i];
            float d2z = sp * st[i];
            float bcx = cx - bx, bcy = cy - by, bcz = cz - bz;
            float inb = 1.f / sqrtf(bcx * bcx + bcy * bcy + bcz * bcz);
            bcx *= inb; bcy *= inb; bcz *= inb;
            float ux = bx - ax, uy = by - ay, uz = bz - az;
            float nx = uy * bcz - uz * bcy;
            float ny = uz * bcx - ux * bcz;
            float nz = ux * bcy - uy * bcx;
            float inn = 1.f / sqrtf(nx * nx + ny * ny + nz * nz);
            nx *= inn; ny *= inn; nz *= inn;
            float mx = ny * bcz - nz * bcy;
            float my = nz * bcx - nx * bcz;
            float mz = nx * bcy - ny * bcx;
            float dx = bcx * d2x + mx * d2y + nx * d2z + cx;
            float dy = bcy * d2x + my * d2y + ny * d2z + cy;
            float dz = bcz * d2x + mz * d2y + nz * d2z + cz;
            int row = 3 + t * 3 + i;
            out[((size_t)row * 32 + b) * 3 + 0] = dx;
            out[((size_t)row * 32 + b) * 3 + 1] = dy;
            out[((size_t)row * 32 + b) * 3 + 2] = dz;
            ax = bx; ay = by; az = bz;
            bx = cx; by = cy; bz = cz;
            cx = dx; cy = dy; cz = dz;
        }
    }
}

extern "C" void kernel_launch(void* const* d_in, const int* in_sizes, int n_in,
                              void* d_out, int out_size, void* d_ws, size_t ws_size,
                              hipStream_t stream)
{
    const float* x     = (const float*)d_in[0];
    const float* wih0f = (const float*)d_in[1];
    const float* whh0f = (const float*)d_in[2];
    const float* b0f   = (const float*)d_in[3];
    const float* wih0b = (const float*)d_in[4];
    const float* whh0b = (const float*)d_in[5];
    const float* b0b   = (const float*)d_in[6];
    const float* wih1f = (const float*)d_in[7];
    const float* whh1f = (const float*)d_in[8];
    const float* b1f   = (const float*)d_in[9];
    const float* wih1b = (const float*)d_in[10];
    const float* whh1b = (const float*)d_in[11];
    const float* b1b   = (const float*)d_in[12];
    const float* linw  = (const float*)d_in[13];
    const float* linb  = (const float*)d_in[14];
    const float* alpha = (const float*)d_in[15];
    (void)in_sizes; (void)n_in; (void)out_size; (void)ws_size;

    char* ws = (char*)d_ws;
    size_t off = 0;
    auto alloc = [&](size_t bytes) -> void* {
        off = (off + 255) & ~(size_t)255;
        void* p = ws + off;
        off += bytes;
        return p;
    };
    u16* xT     = (u16*)alloc((size_t)T_LEN * BATCH * XPAD * 2);          // 2.1 MB
    u16* h1     = (u16*)alloc((size_t)T_LEN * BATCH * HSTR * 2);          // 54.5 MB
    u16* h2     = (u16*)alloc((size_t)T_LEN * BATCH * HSTR * 2);          // 54.5 MB
    u16* P2_0   = (u16*)alloc((size_t)2 * 50 * 2 * 27 * 2 * 64 * 8 * 2);  // 11.06 MB (both dirs)
    u16* P2_0f  = P2_0;
    u16* P2_0b  = P2_0 + (size_t)50 * 2 * 27 * 2 * 64 * 8;
    u16* P2_1f  = (u16*)alloc((size_t)50 * 2 * 25 * 2 * 64 * 8 * 2);      // 5.12 MB
    u16* P2_1b  = (u16*)alloc((size_t)50 * 2 * 25 * 2 * 64 * 8 * 2);
    u16* linwB  = (u16*)alloc((size_t)KCLS * 1600 * 2);
    float* bpk0f = (float*)alloc((size_t)G4 * 4);
    float* bpk0b = (float*)alloc((size_t)G4 * 4);
    u16* hzero  = (u16*)alloc((size_t)BATCH * HSTR * 2);
    float* c1f  = (float*)alloc((size_t)50 * 512 * 4);
    float* c1b  = (float*)alloc((size_t)50 * 512 * 4);
    u16* xgBc   = (u16*)alloc((size_t)WSCAN * BATCH * G4 * 2);            // 6.55 MB
    unsigned* arrive = (unsigned*)alloc((size_t)NBLK * 32 * 4);           // 12.8 KB
    // xgFc aliases the layer-0 weight packs (dead after layer-0 scan): 6.55 MB <= 11.06 MB
    u16* xgFc = P2_0;
    // epilogue buffers alias freed xg chunks
    float* logitsF = (float*)xgFc;   // 1.31 MB <= 6.55 MB
    float* csnF    = (float*)xgBc;   // 0.39 MB <= 6.55 MB

    // ---- prep ----
    k_zero16<<<dim3(32), dim3(256), 0, stream>>>(hzero, BATCH * HSTR);
    k_cvt<<<dim3(64), dim3(256), 0, stream>>>(linw, linwB, KCLS * 1600);
    k_xT<<<dim3(512), dim3(256), 0, stream>>>(x, xT);
    k_pack_all<<<dim3(512, 1, 4), dim3(256), 0, stream>>>(
        whh0f, wih0f, whh0b, wih0b, whh1f, whh1b, P2_0f, P2_0b, P2_1f, P2_1b);
    k_pack_bias<<<dim3(8), dim3(256), 0, stream>>>(b0f, bpk0f);
    k_pack_bias<<<dim3(8), dim3(256), 0, stream>>>(b0b, bpk0b);

    const size_t hstep = (size_t)BATCH * HSTR;

    // ---- layer 0: persistent scan (x-projection folded in) ----
    hipMemsetAsync(arrive, 0, (size_t)NBLK * 32 * 4, stream);
    scan_coop<<<dim3(NBLK), dim3(256), 0, stream>>>(
        27, T_LEN, 0,
        xT, nullptr, nullptr,
        P2_0f, P2_0b, bpk0f, bpk0b,
        hzero, h1, nullptr, nullptr, 0, 0, arrive);

    // ---- layer 1: windowed dual GEMM + persistent scan per window ----
    hipMemsetAsync(arrive, 0, (size_t)NBLK * 32 * 4, stream);  // step values monotone across windows
    for (int w = 0; w < T_LEN / WSCAN; ++w){
        const int s0  = w * WSCAN;
        const int t0f = s0;
        const int t0b = T_LEN - (w + 1) * WSCAN;
        mfma_gemm<<<dim3(G4 / 128, WSCAN * BATCH / 128, 2), dim3(256), 0, stream>>>(
            h1 + (size_t)t0f * hstep, h1 + (size_t)t0b * hstep, HSTR,
            wih1f, wih1b, 1600, b1f, b1b,
            xgFc, xgBc, G4, WSCAN * BATCH, G4, KPAD, 2, 1, 1);
        scan_coop<<<dim3(NBLK), dim3(256), 0, stream>>>(
            25, WSCAN, s0,
            nullptr, xgFc, xgBc,
            P2_1f, P2_1b, nullptr, nullptr,
            hzero, h2, c1f, c1b, (w > 0) ? 1 : 0, 1, arrive);
    }

    // ---- logits (N=20, fp32 out) ----
    mfma_gemm<<<dim3(1, T_LEN * BATCH / 128, 1), dim3(256), 0, stream>>>(
        h2, h2, HSTR, linwB, linwB, 1600, linb, linb,
        logitsF, logitsF, KCLS, T_LEN * BATCH, KCLS, KPAD, 0, 0, 1);

    k_smax_ang<<<dim3(T_LEN), dim3(64), 0, stream>>>(logitsF, alpha, csnF);
    k_coords<<<dim3(1), dim3(64), 0, stream>>>(csnF, (float*)d_out);
}